// Round 1
// 480.800 us; speedup vs baseline: 1.2357x; 1.2357x over previous
//
#include <hip/hip_runtime.h>
#include <stdint.h>
#include <math.h>

// Match numpy's non-fused multiply-add rounding in distance/plane tests:
// a wrong argmin (or a boundary-mask flip) cascades into an O(1) output error.
// R1-R5 passed with absmax 0.0 using exactly these expression forms — keep them.
// p2 is precomputed in pack_points with the SAME expression form (contract off
// file-wide), so packed and unpacked paths are bit-identical.
#pragma clang fp contract(off)

#define BLOCK 1024
#define NW (BLOCK / 64)
#define PT 8                    // points per thread per full-scan step (slab-major)
#define PB 4                    // entries per thread per list-scan step (slab-major)
#define MAX_ITERS 50
#define SOLO_CAP 2048           // below this, wave 0 finishes alone (no barriers)
#define EPS_NORM 1e-8f
#define EPS_SEP (-1e-6f)

// Pack pointcloud into [x,y,z,p2] float4 so the scan does ONE dwordx4 per
// point (R6: VGPR=36 proved the old conditional 3-float loads serialized;
// unconditional clamped float4 loads restore 8-deep MLP per thread).
__global__ void pack_points(const float* __restrict__ pc,
                            float4* __restrict__ pk, int N) {
    const int i = blockIdx.x * blockDim.x + threadIdx.x;
    if (i < N) {
        const float x = pc[3*i+0], y = pc[3*i+1], z = pc[3*i+2];
        float4 v; v.x = x; v.y = y; v.z = z;
        v.w = x*x + y*y + z*z;          // reference's exact p2 form
        pk[i] = v;
    }
}

// One block per target. Survival state = LDS bitmask over N points (R3's
// proven representation; R5's plane-list retest was a serial divergent LDS
// chain and regressed 1.7x).
// Phase A: full-N scans, slab-major x8 (i = s*8192 + j*1024 + tid): coalesced
//          UNCONDITIONAL global float4 loads (R6: live-gating use, not load —
//          the conditional load was the MLP killer), 8 broadcast mask
//          reads/thread, mask written via 8 ballots (lanes 0/32). When the
//          incoming count fits 2*CAP the scan also compacts survivors into an
//          LDS list (shfl prefix-scan + 1 atomic/wave/step).
// Phase B: list-only scans (lane-stride-1 LDS reads: 2-way aliasing is free),
//          re-compacting in place (append positions provably stay below any
//          unread segment).
// Solo tail (verified R5): below SOLO_CAP survivors, waves 1-15 retire; wave 0
// runs all remaining iterations wave-synchronously, zero __syncthreads.
template <bool PACKED>
__global__ __launch_bounds__(BLOCK) void convex_plane_kernel(
    const float* __restrict__ pc, const float4* __restrict__ pk,
    const float* __restrict__ tg,
    float* __restrict__ out, int N, int M, int CAP, int stepsA)
{
    extern __shared__ uint32_t smem[];
    const int tid  = threadIdx.x;
    const int lane = tid & 63;
    const int wv   = tid >> 6;
    const int m    = blockIdx.x;

    const int maskW = stepsA * (PT * BLOCK / 32);  // mask words
    uint32_t* mask  = smem;                        // [maskW]
    int*      list  = (int*)(smem + maskW);        // [CAP]
    float*    red_d = (float*)(list + CAP);        // [NW]
    int*      red_i = (int*)(red_d + NW);          // [NW]
    int*      cw    = red_i + NW;                  // [NW]
    int*      bcast = cw + NW;                     // [2] {argmin idx, count}
    int*      cnt   = bcast + 2;                   // [1] list-append cursor

    const float tx = tg[3*m+0], ty = tg[3*m+1], tz = tg[3*m+2];
    const float t2 = tx*tx + ty*ty + tz*tz;

    float* out_a = out;
    float* out_b = out + (size_t)MAX_ITERS * (size_t)M * 3;

    // point fetch: packed = one dwordx4 (w = precomputed p2, identical bits);
    // fallback = original 3-float path with on-the-fly p2.
    auto ldp = [&](int ip, float& x, float& y, float& z, float& w) {
        if constexpr (PACKED) {
            const float4 v = pk[ip];
            x = v.x; y = v.y; z = v.z; w = v.w;
        } else {
            const float* p = pc + 3 * (size_t)ip;
            x = p[0]; y = p[1]; z = p[2];
            w = x*x + y*y + z*z;
        }
    };

    // cross-wave finish: lexicographic (d2,idx) argmin + count sum; {idx,count}
    // returned to ALL threads via barrier-protected bcast (race-safe).
    auto finish = [&](float dmin, int imin, int mycnt, bool cntFromCursor) -> int2 {
        #pragma unroll
        for (int off = 32; off > 0; off >>= 1) {
            float od = __shfl_down(dmin, off, 64);
            int   oi = __shfl_down(imin, off, 64);
            int   oc = __shfl_down(mycnt, off, 64);
            if (od < dmin || (od == dmin && oi < imin)) { dmin = od; imin = oi; }
            mycnt += oc;
        }
        if (lane == 0) { red_d[wv] = dmin; red_i[wv] = imin; cw[wv] = mycnt; }
        __syncthreads();
        if (wv == 0) {
            float bd = (lane < NW) ? red_d[lane] : INFINITY;
            int   bi = (lane < NW) ? red_i[lane] : 0;
            int   c  = (lane < NW) ? cw[lane]    : 0;
            #pragma unroll
            for (int off = 8; off > 0; off >>= 1) {
                float od = __shfl_down(bd, off, 64);
                int   oi = __shfl_down(bi, off, 64);
                int   oc = __shfl_down(c,  off, 64);
                if (od < bd || (od == bd && oi < bi)) { bd = od; bi = oi; }
                c += oc;
            }
            if (lane == 0) { bcast[0] = bi; bcast[1] = cntFromCursor ? cnt[0] : c; }
        }
        __syncthreads();
        int2 r; r.x = bcast[0]; r.y = bcast[1];
        return r;
    };

    // Phase A: full-N scan, PT points/thread, slab-major.
    // mode 0: all live, no plane test, no mask write (initial argmin)
    // mode 1: all live, test plane, write mask (k=0 cut; mask uninitialized)
    // mode 2: read mask, test plane, write mask
    auto scanA = [&](int mode, bool build,
                     float ax, float ay, float az, float b) -> int2 {
        if (tid == 0) cnt[0] = 0;
        __syncthreads();
        float dmin = INFINITY;
        int   imin = 0;
        int   mycnt = 0;
        for (int s = 0; s < stepsA; ++s) {
            const int ib    = s * PT * BLOCK + tid;
            const int wbase = s * (PT * BLOCK / 32);
            uint32_t live = 0;
            if (mode == 2) {
                #pragma unroll
                for (int j = 0; j < PT; ++j) {       // 8 independent broadcasts
                    uint32_t w = mask[wbase + j * (BLOCK / 32) + (tid >> 5)];
                    live |= ((w >> (tid & 31)) & 1u) << j;
                }
            } else {
                #pragma unroll
                for (int j = 0; j < PT; ++j)
                    if (ib + j * BLOCK < N) live |= (1u << j);
            }
            // UNCONDITIONAL clamped loads: all 8 issued before any use (MLP=8).
            // Dead/tail lanes re-read point N-1; the live mask gates all uses.
            float px[PT], py[PT], pz[PT], pw[PT];
            #pragma unroll
            for (int j = 0; j < PT; ++j) {
                int ip = ib + j * BLOCK;
                ip = ip < N ? ip : N - 1;
                ldp(ip, px[j], py[j], pz[j], pw[j]);
            }
            uint32_t keepm = 0;
            #pragma unroll
            for (int j = 0; j < PT; ++j) {
                if ((live >> j) & 1u) {
                    bool keep;
                    if (mode == 0) keep = true;
                    else {
                        float dt = ax*px[j] + ay*py[j] + az*pz[j] - b;
                        keep = (dt < EPS_SEP);       // !(dt >= EPS_SEP)
                    }
                    if (keep) {
                        keepm |= (1u << j);
                        float tp = tx*px[j] + ty*py[j] + tz*pz[j];
                        float d2 = t2 + pw[j] - 2.0f*tp;  // reference's exact form
                        // per-thread i ascends over (s,j): strict < = first-index
                        if (d2 < dmin) { dmin = d2; imin = ib + j * BLOCK; }
                    }
                }
            }
            if (mode != 0) {
                #pragma unroll
                for (int j = 0; j < PT; ++j) {       // mask write: 2 lanes/wave/j
                    unsigned long long bal = __ballot(((keepm >> j) & 1u) != 0u);
                    const int widx = wbase + j * (BLOCK / 32) + (wv << 1);
                    if (lane == 0)       mask[widx]     = (uint32_t)bal;
                    else if (lane == 32) mask[widx + 1] = (uint32_t)(bal >> 32);
                }
            }
            mycnt += (int)__popc(keepm);
            if (build) {                             // compact survivors
                int c = (int)__popc(keepm);
                int incl = c;
                #pragma unroll
                for (int off = 1; off < 64; off <<= 1) {
                    int o = __shfl_up(incl, off, 64);
                    if (lane >= off) incl += o;
                }
                const int excl = incl - c;
                const int tot  = __shfl(incl, 63, 64);
                int wb = 0;
                if (lane == 0) wb = atomicAdd(cnt, tot);
                wb = __shfl(wb, 0, 64);
                int pos = wb + excl;
                #pragma unroll
                for (int j = 0; j < PT; ++j) {
                    if ((keepm >> j) & 1u) {
                        if (pos < CAP) list[pos] = ib + j * BLOCK;
                        ++pos;
                    }
                }
            }
        }
        return finish(dmin, imin, mycnt, false);
    };

    // Phase B: list scan, slab-major, in-place re-compaction. Safe: per
    // segment, all reads complete (barrier) before appends, and append
    // positions stay strictly below any unread segment.
    auto scanB = [&](int count, float ax, float ay, float az, float b) -> int2 {
        if (tid == 0) cnt[0] = 0;
        __syncthreads();
        float dmin = INFINITY;
        int   imin = 0;
        const int per = BLOCK * PB;
        const int bsteps = (count + per - 1) / per;
        for (int s = 0; s < bsteps; ++s) {
            int jv[PB]; float d2v[PB];
            uint32_t keepm = 0;
            #pragma unroll
            for (int q = 0; q < PB; ++q) {
                const int e = s * per + q * BLOCK + tid;   // lane-stride 1
                if (e < count) {
                    const int j = list[e];
                    jv[q] = j;
                    float px, py, pz, p2;
                    ldp(j, px, py, pz, p2);
                    float dt = ax*px + ay*py + az*pz - b;
                    if (dt < EPS_SEP) {
                        keepm |= (1u << q);
                        float tp = tx*px + ty*py + tz*pz;
                        d2v[q] = t2 + p2 - 2.0f*tp;
                    }
                }
            }
            __syncthreads();                         // reads done before appends
            int c = (int)__popc(keepm);
            int incl = c;
            #pragma unroll
            for (int off = 1; off < 64; off <<= 1) {
                int o = __shfl_up(incl, off, 64);
                if (lane >= off) incl += o;
            }
            const int excl = incl - c;
            const int tot  = __shfl(incl, 63, 64);
            int wb = 0;
            if (lane == 0) wb = atomicAdd(cnt, tot);
            wb = __shfl(wb, 0, 64);
            int pos = wb + excl;
            #pragma unroll
            for (int q = 0; q < PB; ++q) {
                if ((keepm >> q) & 1u) {
                    list[pos] = jv[q];
                    // list order arbitrary -> lexicographic for exact ties
                    if (d2v[q] < dmin || (d2v[q] == dmin && jv[q] < imin)) {
                        dmin = d2v[q]; imin = jv[q];
                    }
                    ++pos;
                }
            }
        }
        __syncthreads();                             // all appends/atomics done
        return finish(dmin, imin, 0, true);          // count from cursor
    };

    bool comp = false;
    int2 rc = scanA(0, false, 0.f, 0.f, 0.f, 0.f);
    int idx = rc.x, count = rc.y;                    // count = N here

    for (int k = 0; k < MAX_ITERS; ++k) {
        // Solo tail (verified R5): wave 0 finishes barrier-free.
        if (comp && count <= SOLO_CAP) {
            if (wv != 0) return;                     // LDS persists while any wave lives
            for (; k < MAX_ITERS; ++k) {
                float cx, cy, cz, cw4;
                ldp(idx, cx, cy, cz, cw4);
                const float vx = cx - tx, vy = cy - ty, vz = cz - tz;
                const float nrm = sqrtf(vx*vx + vy*vy + vz*vz);
                const float den = nrm + EPS_NORM;
                const float ax = vx / den, ay = vy / den, az = vz / den;
                const float b  = ax*cx + ay*cy + az*cz;
                if (count == 0) {                    // constant tail: bulk write
                    for (int q = lane; q < MAX_ITERS - k; q += 64) {
                        const int kk = k + q;
                        const size_t oa = ((size_t)kk * M + m) * 3;
                        out_a[oa+0] = ax; out_a[oa+1] = ay; out_a[oa+2] = az;
                        out_b[(size_t)kk * M + m] = b;
                    }
                    return;
                }
                if (lane == 0) {
                    const size_t oa = ((size_t)k * M + m) * 3;
                    out_a[oa+0] = ax; out_a[oa+1] = ay; out_a[oa+2] = az;
                    out_b[(size_t)k * M + m] = b;
                }
                if (k + 1 < MAX_ITERS) {
                    float dmin = INFINITY; int imin = 0; int wcur = 0;
                    for (int e0 = 0; e0 < count; e0 += 64) {
                        const int e = e0 + lane;
                        bool keep = false; int j = 0; float d2v = 0.f;
                        if (e < count) {
                            j = list[e];
                            float px, py, pz, p2;
                            ldp(j, px, py, pz, p2);
                            float dt = ax*px + ay*py + az*pz - b;
                            if (dt < EPS_SEP) {
                                keep = true;
                                float tp = tx*px + ty*py + tz*pz;
                                d2v = t2 + p2 - 2.0f*tp;
                            }
                        }
                        // in-place compact: pos < wcur+64 <= e0+64, and chunk
                        // [e0,e0+64) is already in registers.
                        unsigned long long bal = __ballot(keep);
                        int pos = wcur + (int)__popcll(bal & ((1ull << lane) - 1ull));
                        if (keep) {
                            list[pos] = j;
                            if (d2v < dmin || (d2v == dmin && j < imin)) {
                                dmin = d2v; imin = j;
                            }
                        }
                        wcur += (int)__popcll(bal);
                    }
                    #pragma unroll
                    for (int off = 32; off > 0; off >>= 1) {
                        float od = __shfl_down(dmin, off, 64);
                        int   oi = __shfl_down(imin, off, 64);
                        if (od < dmin || (od == dmin && oi < imin)) { dmin = od; imin = oi; }
                    }
                    idx = __shfl(imin, 0, 64);
                    count = wcur;                    // uniform across lanes
                }
            }
            return;
        }

        float cx, cy, cz, cw4;
        ldp(idx, cx, cy, cz, cw4);
        const float vx = cx - tx, vy = cy - ty, vz = cz - tz;
        const float nrm = sqrtf(vx*vx + vy*vy + vz*vz);
        const float den = nrm + EPS_NORM;
        const float ax = vx / den, ay = vy / den, az = vz / den;
        const float b  = ax*cx + ay*cy + az*cz;      // b = sum(a * closest)

        if (count == 0) {                            // constant tail: bulk write
            for (int q = tid; q < MAX_ITERS - k; q += BLOCK) {
                const int kk = k + q;
                const size_t oa = ((size_t)kk * M + m) * 3;
                out_a[oa+0] = ax; out_a[oa+1] = ay; out_a[oa+2] = az;
                out_b[(size_t)kk * M + m] = b;
            }
            return;
        }
        if (tid == 0) {
            const size_t oa = ((size_t)k * M + m) * 3;
            out_a[oa+0] = ax; out_a[oa+1] = ay; out_a[oa+2] = az;
            out_b[(size_t)k * M + m] = b;
        }
        if (k + 1 < MAX_ITERS) {                     // last update unobservable
            if (comp) {
                rc = scanB(count, ax, ay, az, b);
            } else {
                const bool build = (count <= 2 * CAP);
                rc = scanA(k == 0 ? 1 : 2, build, ax, ay, az, b);
                if (build && rc.y <= CAP) comp = true;
            }
            idx = rc.x; count = rc.y;
        }
    }
}

extern "C" void kernel_launch(void* const* d_in, const int* in_sizes, int n_in,
                              void* d_out, int out_size, void* d_ws, size_t ws_size,
                              hipStream_t stream) {
    const float* pc = (const float*)d_in[0];
    const float* tg = (const float*)d_in[1];
    float* out = (float*)d_out;
    const int N = in_sizes[0] / 3;
    const int M = in_sizes[1] / 3;
    const int stepsA = (N + BLOCK * PT - 1) / (BLOCK * PT);
    const size_t maskB  = (size_t)stepsA * (PT * BLOCK / 32) * sizeof(uint32_t);
    const size_t fixedB = NW * (2 * sizeof(int) + sizeof(float)) + 3 * sizeof(int);
    const size_t packB  = (size_t)N * sizeof(float4);
    const bool packed = (d_ws != nullptr) && (ws_size >= packB);

    int CAP = 32768;                                 // 128 KB list; total ~157 KB LDS
    size_t smem = maskB + (size_t)CAP * sizeof(int) + fixedB;
    const void* fn = packed ? (const void*)convex_plane_kernel<true>
                            : (const void*)convex_plane_kernel<false>;
    if (hipFuncSetAttribute(fn, hipFuncAttributeMaxDynamicSharedMemorySize,
                            (int)smem) != hipSuccess) {
        CAP = 8192;                                  // stay within default 64 KB
        smem = maskB + (size_t)CAP * sizeof(int) + fixedB;
    }
    if (packed) {
        float4* pk = (float4*)d_ws;
        pack_points<<<(N + 255) / 256, 256, 0, stream>>>(pc, pk, N);
        convex_plane_kernel<true><<<M, BLOCK, smem, stream>>>(
            pc, pk, tg, out, N, M, CAP, stepsA);
    } else {
        convex_plane_kernel<false><<<M, BLOCK, smem, stream>>>(
            pc, nullptr, tg, out, N, M, CAP, stepsA);
    }
}